// Round 15
// baseline (644.189 us; speedup 1.0000x reference)
//
#include <hip/hip_runtime.h>
#include <hip/hip_cooperative_groups.h>
#include <cmath>

namespace cg = cooperative_groups;

typedef __attribute__((ext_vector_type(8))) __bf16 bf16x8;
typedef __attribute__((ext_vector_type(4))) __bf16 bf16x4;
typedef __attribute__((ext_vector_type(4))) float  f32x4;

constexpr int NB   = 4;
constexpr int SEQ  = 2048;
constexpr int DM   = 256;
constexpr int NH   = 8;
constexpr int DH   = 32;
constexpr int DFF  = 1024;
constexpr int MTOK = NB * SEQ;  // 8192

struct MegaArgs {
  const float* tokens; const unsigned char* mask;
  const float* ln1g; const float* ln1b;
  const float* wq; const float* bq; const float* wk; const float* bk;
  const float* wv; const float* bv; const float* wo; const float* bo;
  const float* ln2g; const float* ln2b;
  const float* w1; const float* b1; const float* w2; const float* b2;
  float* out;
  __bf16* wqkvT; __bf16* woT; __bf16* w1T; __bf16* w2T;
  __bf16* xn1; __bf16* qb; __bf16* kb; __bf16* vt; __bf16* xn2; __bf16* hbuf;
  float* lpart; float* x1; float* Opart; float* madd;
};

// ---------------- LayerNorm row: fp32[256] -> bf16[256], one wave ----------------
__device__ __forceinline__ void ln_row(const float* __restrict__ xr,
                                       const float* __restrict__ g,
                                       const float* __restrict__ b,
                                       __bf16* __restrict__ outr, int lane) {
  f32x4 v = *(const f32x4*)(xr + lane * 4);
  float s  = v[0] + v[1] + v[2] + v[3];
  float sq = v[0]*v[0] + v[1]*v[1] + v[2]*v[2] + v[3]*v[3];
  #pragma unroll
  for (int off = 1; off < 64; off <<= 1) {
    s  += __shfl_xor(s, off);
    sq += __shfl_xor(sq, off);
  }
  float mu  = s * (1.0f / DM);
  float var = sq * (1.0f / DM) - mu * mu;
  float rs  = rsqrtf(var + 1e-5f);
  f32x4 gv = *(const f32x4*)(g + lane * 4);
  f32x4 bv = *(const f32x4*)(b + lane * 4);
  bf16x4 o;
  #pragma unroll
  for (int i = 0; i < 4; ++i) o[i] = (__bf16)((v[i] - mu) * rs * gv[i] + bv[i]);
  *(bf16x4*)(outr + lane * 4) = o;
}

// ---------------- Prep virtual-block: weight transposes / madd / LN1 ----------------
__device__ void prep_vb(int bid, int tid, char* smem, const MegaArgs& a) {
  if (bid >= 800) {
    int row = (bid - 800) * 4 + (tid >> 6);
    ln_row(a.tokens + (size_t)row * DM, a.ln1g, a.ln1b, a.xn1 + (size_t)row * DM, tid & 63);
    return;
  }
  if (bid >= 768) {
    int idx = (bid - 768) * 256 + tid;
    a.madd[idx] = a.mask[idx] ? -__builtin_inff() : 0.0f;
    return;
  }
  float (*tile)[33] = (float(*)[33])smem;
  const float* W; __bf16* Wt; int K, N, n0, k0;
  if (bid < 256) {
    int z = bid >> 6, local = bid & 63;
    K = 256; N = 256;
    n0 = (local & 7) * 32; k0 = (local >> 3) * 32;
    if      (z == 0) { W = a.wq; Wt = a.wqkvT;          }
    else if (z == 1) { W = a.wk; Wt = a.wqkvT + 65536;  }
    else if (z == 2) { W = a.wv; Wt = a.wqkvT + 131072; }
    else             { W = a.wo; Wt = a.woT;            }
  } else if (bid < 512) {
    int local = bid - 256;
    W = a.w1; Wt = a.w1T; K = 256; N = 1024;
    n0 = (local & 31) * 32; k0 = (local >> 5) * 32;
  } else {
    int local = bid - 512;
    W = a.w2; Wt = a.w2T; K = 1024; N = 256;
    n0 = (local & 7) * 32; k0 = (local >> 3) * 32;
  }
  {
    int kl = tid >> 3, n4 = (tid & 7) * 4;
    f32x4 v = *(const f32x4*)(W + (size_t)(k0 + kl) * N + n0 + n4);
    tile[kl][n4 + 0] = v[0]; tile[kl][n4 + 1] = v[1];
    tile[kl][n4 + 2] = v[2]; tile[kl][n4 + 3] = v[3];
  }
  __syncthreads();
  {
    int nl = tid >> 3, k4 = (tid & 7) * 4;
    bf16x4 o;
    #pragma unroll
    for (int i = 0; i < 4; ++i) o[i] = (__bf16)tile[k4 + i][nl];
    *(bf16x4*)(Wt + (size_t)(n0 + nl) * K + k0 + k4) = o;
  }
  __syncthreads();
}

// ---------------- GEMM phase (R13 gemm_bt body), virtual block (bx,by) ----------------
template<int BM, int BN, int EP, int AF>
__device__ void gemm_phase(int bx, int by, int tid, char* smem,
    const __bf16* __restrict__ A, const __bf16* __restrict__ Bt, int N, int K,
    const float* __restrict__ bias,
    const float* __restrict__ bq, const float* __restrict__ bk, const float* __restrict__ bv,
    const float* __restrict__ resid, float* __restrict__ outf, __bf16* __restrict__ outb,
    __bf16* __restrict__ outq, __bf16* __restrict__ outk, __bf16* __restrict__ outv,
    const float* __restrict__ Af, const float* __restrict__ lpart) {
  constexpr int MT = BM / 32, NT = BN / 32;
  constexpr int AP = BM / 32, BP = BN / 32;
  __bf16* As = (__bf16*)smem;
  __bf16* Bs = (__bf16*)(smem + (size_t)BM * 64 * sizeof(__bf16));
  int wave = tid >> 6, lane = tid & 63;
  int wm = wave >> 1, wn = wave & 1;
  int quad = lane >> 4, l16 = lane & 15;
  int m0 = bx * BM, n0 = by * BN;
  int lrow = lane >> 3;
  int lcg  = ((lane & 7) ^ lrow) * 8;

  auto loadA = [&](int rbase, int kcol) -> bf16x8 {
    int gr = m0 + rbase + lrow;
    if constexpr (AF == 0) {
      return *(const bf16x8*)(A + (size_t)gr * K + kcol);
    } else {
      const float* p0 = Af + (size_t)gr * K + kcol;
      const float* p1 = p0 + (size_t)MTOK * DM;
      f32x4 a0 = *(const f32x4*)p0, a0b = *(const f32x4*)(p0 + 4);
      f32x4 a1 = *(const f32x4*)p1, a1b = *(const f32x4*)(p1 + 4);
      int bb = gr >> 11, tok = gr & 2047, hh = kcol >> 5;
      float l = lpart[((size_t)bb * NH + hh) * SEQ + tok] +
                lpart[(((size_t)NB + bb) * NH + hh) * SEQ + tok];
      float inv = 1.0f / l;
      bf16x8 o;
      #pragma unroll
      for (int i = 0; i < 4; ++i) {
        o[i]     = (__bf16)((a0[i]  + a1[i])  * inv);
        o[i + 4] = (__bf16)((a0b[i] + a1b[i]) * inv);
      }
      return o;
    }
  };

  f32x4 acc[MT][NT];
  #pragma unroll
  for (int mt = 0; mt < MT; ++mt)
    #pragma unroll
    for (int nt = 0; nt < NT; ++nt)
      #pragma unroll
      for (int r = 0; r < 4; ++r) acc[mt][nt][r] = 0.0f;

  bf16x8 ap[AP], bp[BP];
  #pragma unroll
  for (int i = 0; i < AP; ++i) ap[i] = loadA(wave * (BM / 4) + i * 8, lcg);
  #pragma unroll
  for (int i = 0; i < BP; ++i) {
    int rbase = wave * (BN / 4) + i * 8;
    bp[i] = *(const bf16x8*)(Bt + (size_t)(n0 + rbase + lrow) * K + lcg);
  }
  #pragma unroll
  for (int i = 0; i < AP; ++i) {
    int rbase = wave * (BM / 4) + i * 8;
    *(bf16x8*)&As[rbase * 64 + lane * 8] = ap[i];
  }
  #pragma unroll
  for (int i = 0; i < BP; ++i) {
    int rbase = wave * (BN / 4) + i * 8;
    *(bf16x8*)&Bs[rbase * 64 + lane * 8] = bp[i];
  }
  __syncthreads();

  for (int kt = 0; kt < K; kt += 64) {
    bool more = (kt + 64) < K;
    if (more) {
      #pragma unroll
      for (int i = 0; i < AP; ++i) ap[i] = loadA(wave * (BM / 4) + i * 8, kt + 64 + lcg);
      #pragma unroll
      for (int i = 0; i < BP; ++i) {
        int rbase = wave * (BN / 4) + i * 8;
        bp[i] = *(const bf16x8*)(Bt + (size_t)(n0 + rbase + lrow) * K + kt + 64 + lcg);
      }
    }
    #pragma unroll
    for (int ks = 0; ks < 2; ++ks) {
      bf16x8 af[MT], bfr[NT];
      #pragma unroll
      for (int mt = 0; mt < MT; ++mt) {
        int row = wm * (BM / 2) + mt * 16 + l16;
        af[mt] = *(const bf16x8*)&As[row * 64 + (((ks * 4 + quad) ^ (l16 & 7)) * 8)];
      }
      #pragma unroll
      for (int nt = 0; nt < NT; ++nt) {
        int row = wn * (BN / 2) + nt * 16 + l16;
        bfr[nt] = *(const bf16x8*)&Bs[row * 64 + (((ks * 4 + quad) ^ (l16 & 7)) * 8)];
      }
      #pragma unroll
      for (int mt = 0; mt < MT; ++mt)
        #pragma unroll
        for (int nt = 0; nt < NT; ++nt)
          acc[mt][nt] = __builtin_amdgcn_mfma_f32_16x16x32_bf16(af[mt], bfr[nt], acc[mt][nt], 0, 0, 0);
    }
    if (more) {
      __syncthreads();
      #pragma unroll
      for (int i = 0; i < AP; ++i) {
        int rbase = wave * (BM / 4) + i * 8;
        *(bf16x8*)&As[rbase * 64 + lane * 8] = ap[i];
      }
      #pragma unroll
      for (int i = 0; i < BP; ++i) {
        int rbase = wave * (BN / 4) + i * 8;
        *(bf16x8*)&Bs[rbase * 64 + lane * 8] = bp[i];
      }
      __syncthreads();
    }
  }

  #pragma unroll
  for (int mt = 0; mt < MT; ++mt)
  #pragma unroll
  for (int nt = 0; nt < NT; ++nt)
  #pragma unroll
  for (int r = 0; r < 4; ++r) {
    int gm = m0 + wm * (BM / 2) + mt * 16 + quad * 4 + r;
    int gn = n0 + wn * (BN / 2) + nt * 16 + l16;
    float v = acc[mt][nt][r];
    if constexpr (EP == 0) {
      int which = gn >> 8, nn = gn & 255;
      const float* bp2 = which == 0 ? bq : (which == 1 ? bk : bv);
      v += bp2[nn];
      int h = nn >> 5, hd = nn & 31;
      int bb = gm >> 11, tok = gm & 2047;
      if (which == 2) {
        outv[(((size_t)(bb * NH + h)) * DH + hd) * SEQ + tok] = (__bf16)v;
      } else {
        __bf16* dst = which == 0 ? outq : outk;
        dst[(((size_t)(bb * NH + h)) * SEQ + tok) * DH + hd] = (__bf16)v;
      }
    } else if constexpr (EP == 1) {
      v += bias[gn] + resid[(size_t)gm * N + gn];
      outf[(size_t)gm * N + gn] = v;
    } else {
      v += bias[gn];
      float v2 = v * v;
      float t = __builtin_amdgcn_exp2f(v * (2.3022082f + 0.10294324f * v2));
      outb[(size_t)gm * N + gn] = (__bf16)(v * t * __builtin_amdgcn_rcpf(t + 1.0f));
    }
  }
  __syncthreads();
}

// ---------------- Attention phase (R13 body): 32 q/wave, 128-key stages, split-K=2 ----------------
__device__ void attn_phase(int qc, int bh, int half, int tid, char* smem, const MegaArgs& a) {
  constexpr float C2 = 0.2550350030061664f;  // (1/sqrt(32)) * log2(e)
  __bf16 (*Ks)[36]        = (__bf16(*)[36])smem;                  // 9216 B
  __bf16 (*Vs)[132]       = (__bf16(*)[132])(smem + 9216);        // 8448 B
  __bf16 (*Ps)[2][16][68] = (__bf16(*)[2][16][68])(smem + 17664); // 17408 B
  int q0 = qc * 128;
  int b  = bh >> 3, h = bh & 7;
  int wave = tid >> 6, lane = tid & 63;
  int quad = lane >> 4, l16 = lane & 15;
  const __bf16* Qb = a.qb + (size_t)bh * SEQ * DH;
  const __bf16* Kb = a.kb + (size_t)bh * SEQ * DH;
  const __bf16* Vb = a.vt + (size_t)bh * DH * SEQ;
  const float* maddb = a.madd + b * SEQ;
  int qw = q0 + wave * 32;
  int kbase = half * (SEQ / 2);

  bf16x8 qf[2];
  #pragma unroll
  for (int qg = 0; qg < 2; ++qg)
    qf[qg] = *(const bf16x8*)(Qb + (size_t)(qw + qg * 16 + l16) * DH + quad * 8);

  bf16x8 ones;
  #pragma unroll
  for (int i = 0; i < 8; ++i) ones[i] = (__bf16)1.0f;

  f32x4 o[2][2], ol[2];
  #pragma unroll
  for (int qg = 0; qg < 2; ++qg) {
    #pragma unroll
    for (int nt = 0; nt < 2; ++nt)
      #pragma unroll
      for (int r = 0; r < 4; ++r) o[qg][nt][r] = 0.0f;
    #pragma unroll
    for (int r = 0; r < 4; ++r) ol[qg][r] = 0.0f;
  }

  f32x4 zf; zf[0] = zf[1] = zf[2] = zf[3] = 0.0f;

  for (int st = 0; st < 8; ++st) {
    int kb0 = kbase + st * 128;
    __syncthreads();
    #pragma unroll
    for (int p = 0; p < 2; ++p) {
      int c = p * 256 + tid, row = c >> 2, cg2 = (c & 3) * 8;
      *(bf16x8*)&Ks[row][cg2] = *(const bf16x8*)(Kb + (size_t)(kb0 + row) * DH + cg2);
    }
    #pragma unroll
    for (int p = 0; p < 2; ++p) {
      int c = p * 256 + tid, row = c >> 4, cg2 = (c & 15) * 8;
      *(bf16x8*)&Vs[row][cg2] = *(const bf16x8*)(Vb + (size_t)row * SEQ + kb0 + cg2);
    }
    __syncthreads();

    #pragma unroll
    for (int sub = 0; sub < 2; ++sub) {
      int kl = sub * 64;
      f32x4 s[2][4];
      #pragma unroll
      for (int mt = 0; mt < 4; ++mt) {
        bf16x8 kf = *(const bf16x8*)&Ks[kl + mt * 16 + l16][quad * 8];
        s[0][mt] = __builtin_amdgcn_mfma_f32_16x16x32_bf16(kf, qf[0], zf, 0, 0, 0);
        s[1][mt] = __builtin_amdgcn_mfma_f32_16x16x32_bf16(kf, qf[1], zf, 0, 0, 0);
      }
      #pragma unroll
      for (int mt = 0; mt < 4; ++mt) {
        f32x4 md = *(const f32x4*)(maddb + kb0 + kl + mt * 16 + quad * 4);
        #pragma unroll
        for (int qg = 0; qg < 2; ++qg) {
          bf16x4 pv;
          #pragma unroll
          for (int r = 0; r < 4; ++r)
            pv[r] = (__bf16)__builtin_amdgcn_exp2f(fmaf(s[qg][mt][r], C2, md[r]));
          *(bf16x4*)&Ps[wave][qg][l16][mt * 16 + quad * 4] = pv;
        }
      }
      #pragma unroll
      for (int ks = 0; ks < 2; ++ks) {
        bf16x8 vf[2];
        #pragma unroll
        for (int nt = 0; nt < 2; ++nt)
          vf[nt] = *(const bf16x8*)&Vs[nt * 16 + l16][kl + ks * 32 + quad * 8];
        #pragma unroll
        for (int qg = 0; qg < 2; ++qg) {
          bf16x8 pf = *(const bf16x8*)&Ps[wave][qg][l16][ks * 32 + quad * 8];
          #pragma unroll
          for (int nt = 0; nt < 2; ++nt)
            o[qg][nt] = __builtin_amdgcn_mfma_f32_16x16x32_bf16(pf, vf[nt], o[qg][nt], 0, 0, 0);
          ol[qg] = __builtin_amdgcn_mfma_f32_16x16x32_bf16(pf, ones, ol[qg], 0, 0, 0);
        }
      }
    }
  }

  float* Op = a.Opart + (size_t)half * MTOK * DM;
  #pragma unroll
  for (int qg = 0; qg < 2; ++qg) {
    #pragma unroll
    for (int nt = 0; nt < 2; ++nt)
      #pragma unroll
      for (int r = 0; r < 4; ++r) {
        int q   = qw + qg * 16 + quad * 4 + r;
        int col = h * DH + nt * 16 + l16;
        Op[((size_t)(b * SEQ + q)) * DM + col] = o[qg][nt][r];
      }
    if (l16 == 0) {
      #pragma unroll
      for (int r = 0; r < 4; ++r)
        a.lpart[((((size_t)half * NB + b) * NH) + h) * SEQ + qw + qg * 16 + quad * 4 + r] = ol[qg][r];
    }
  }
  __syncthreads();
}

// ---------------- Phase dispatch helpers (shared by mega + fallback) ----------------
__device__ __forceinline__ void phase_qkv(int vb, int tid, char* smem, const MegaArgs& a) {
  gemm_phase<128, 64, 0, 0>(vb & 63, vb >> 6, tid, smem,
      a.xn1, a.wqkvT, 768, 256, nullptr, a.bq, a.bk, a.bv,
      nullptr, nullptr, nullptr, a.qb, a.kb, a.vt, nullptr, nullptr);
}
__device__ __forceinline__ void phase_wo(int vb, int tid, char* smem, const MegaArgs& a) {
  gemm_phase<64, 64, 1, 1>(vb & 127, vb >> 7, tid, smem,
      nullptr, a.woT, 256, 256, a.bo, nullptr, nullptr, nullptr,
      a.tokens, a.x1, nullptr, nullptr, nullptr, nullptr, a.Opart, a.lpart);
}
__device__ __forceinline__ void phase_ff1(int vb, int tid, char* smem, const MegaArgs& a) {
  gemm_phase<128, 64, 2, 0>(vb & 63, vb >> 6, tid, smem,
      a.xn2, a.w1T, 1024, 256, a.b1, nullptr, nullptr, nullptr,
      nullptr, nullptr, a.hbuf, nullptr, nullptr, nullptr, nullptr, nullptr);
}
__device__ __forceinline__ void phase_ff2(int vb, int tid, char* smem, const MegaArgs& a) {
  gemm_phase<64, 64, 1, 0>(vb & 127, vb >> 7, tid, smem,
      a.hbuf, a.w2T, 256, 1024, a.b2, nullptr, nullptr, nullptr,
      a.x1, a.out, nullptr, nullptr, nullptr, nullptr, nullptr, nullptr);
}

// ---------------- Fused layer: grid-stride phases, 6 grid syncs, ONE dispatch ----------------
__global__ __launch_bounds__(256, 4) void mega_kernel(MegaArgs a) {
  __shared__ __align__(16) char smem[35072];
  cg::grid_group grid = cg::this_grid();
  int rb = blockIdx.x, nb = gridDim.x;
  int tid = threadIdx.x;

  for (int vb = rb; vb < 2848; vb += nb) prep_vb(vb, tid, smem, a);
  grid.sync();
  for (int vb = rb; vb < 768; vb += nb) phase_qkv(vb, tid, smem, a);
  grid.sync();
  for (int vb = rb; vb < 1024; vb += nb)
    attn_phase(vb & 15, (vb >> 4) & 31, vb >> 9, tid, smem, a);
  grid.sync();
  for (int vb = rb; vb < 512; vb += nb) phase_wo(vb, tid, smem, a);
  grid.sync();
  for (int vb = rb; vb < 2048; vb += nb) {
    int row = vb * 4 + (tid >> 6);
    ln_row(a.x1 + (size_t)row * DM, a.ln2g, a.ln2b, a.xn2 + (size_t)row * DM, tid & 63);
  }
  grid.sync();
  for (int vb = rb; vb < 1024; vb += nb) phase_ff1(vb, tid, smem, a);
  grid.sync();
  for (int vb = rb; vb < 512; vb += nb) phase_ff2(vb, tid, smem, a);
}

// ---------------- Fallback wrappers (R13 grids, same device code) ----------------
__global__ __launch_bounds__(256) void prep_k(MegaArgs a) {
  __shared__ __align__(16) char smem[4224];
  prep_vb(blockIdx.x, threadIdx.x, smem, a);
}
__global__ __launch_bounds__(256) void qkv_k(MegaArgs a) {
  __shared__ __align__(16) char smem[24576];
  phase_qkv(blockIdx.y * 64 + blockIdx.x, threadIdx.x, smem, a);
}
__global__ __launch_bounds__(256) void attn_k(MegaArgs a) {
  __shared__ __align__(16) char smem[35072];
  attn_phase(blockIdx.x, blockIdx.y, blockIdx.z, threadIdx.x, smem, a);
}
__global__ __launch_bounds__(256) void wo_k(MegaArgs a) {
  __shared__ __align__(16) char smem[16384];
  phase_wo(blockIdx.y * 128 + blockIdx.x, threadIdx.x, smem, a);
}
__global__ __launch_bounds__(256) void ln2_k(MegaArgs a) {
  int row = blockIdx.x * 4 + (threadIdx.x >> 6);
  ln_row(a.x1 + (size_t)row * DM, a.ln2g, a.ln2b, a.xn2 + (size_t)row * DM, threadIdx.x & 63);
}
__global__ __launch_bounds__(256) void ff1_k(MegaArgs a) {
  __shared__ __align__(16) char smem[24576];
  phase_ff1(blockIdx.y * 64 + blockIdx.x, threadIdx.x, smem, a);
}
__global__ __launch_bounds__(256) void ff2_k(MegaArgs a) {
  __shared__ __align__(16) char smem[16384];
  phase_ff2(blockIdx.y * 128 + blockIdx.x, threadIdx.x, smem, a);
}

// ---------------- launcher ----------------
extern "C" void kernel_launch(void* const* d_in, const int* in_sizes, int n_in,
                              void* d_out, int out_size, void* d_ws, size_t ws_size,
                              hipStream_t stream) {
  char* ws = (char*)d_ws;
  MegaArgs a;
  a.tokens = (const float*)d_in[0];
  a.mask   = (const unsigned char*)d_in[1];
  a.ln1g = (const float*)d_in[2];  a.ln1b = (const float*)d_in[3];
  a.wq = (const float*)d_in[4];    a.bq = (const float*)d_in[5];
  a.wk = (const float*)d_in[6];    a.bk = (const float*)d_in[7];
  a.wv = (const float*)d_in[8];    a.bv = (const float*)d_in[9];
  a.wo = (const float*)d_in[10];   a.bo = (const float*)d_in[11];
  a.ln2g = (const float*)d_in[12]; a.ln2b = (const float*)d_in[13];
  a.w1 = (const float*)d_in[14];   a.b1 = (const float*)d_in[15];
  a.w2 = (const float*)d_in[16];   a.b2 = (const float*)d_in[17];
  a.out = (float*)d_out;

  a.wqkvT = (__bf16*)(ws + 0);            // [768][256]
  a.woT   = (__bf16*)(ws + 393216);       // [256][256]
  a.w1T   = (__bf16*)(ws + 524288);       // [1024][256]
  a.w2T   = (__bf16*)(ws + 1048576);      // [256][1024]
  a.xn1   = (__bf16*)(ws + 1572864);      // [8192][256] (dead after QKV)
  a.lpart = (float*)(ws + 1572864);       // reuses xn1 region (written by attn, after xn1 dead)
  a.qb    = (__bf16*)(ws + 5767168);      // [32][2048][32]
  a.kb    = (__bf16*)(ws + 9961472);
  a.vt    = (__bf16*)(ws + 18350080);     // [32][32][2048]
  a.x1    = (float*)(ws + 26738688);      // [8192][256] fp32
  a.xn2   = (__bf16*)(ws + 35127296);     // [8192][256]
  a.hbuf  = (__bf16*)(ws + 39321600);     // [8192][1024] (FF1 out)
  a.Opart = (float*)(ws + 39321600);      // [2][8192][256] fp32, lifetime-disjoint w/ hbuf
  a.madd  = (float*)(ws + 56098816);      // [4][2048] fp32

  // size cooperative grid from actual occupancy (don't assume 4 blocks/CU)
  int maxB = 0;
  hipError_t oe = hipOccupancyMaxActiveBlocksPerMultiprocessor(&maxB, mega_kernel, 256, 0);
  int grid = 1024;
  if (oe == hipSuccess && maxB >= 1) {
    int g = maxB * 256;          // 256 CUs
    if (g < grid) grid = g;
  }

  void* kargs[] = { (void*)&a };
  hipError_t err = hipLaunchCooperativeKernel((const void*)mega_kernel, dim3(grid), dim3(256),
                                              kargs, 0, stream);
  if (err != hipSuccess) {
    // deterministic fallback: R13-equivalent 7-dispatch pipeline (same device code)
    prep_k<<<2848, 256, 0, stream>>>(a);
    qkv_k<<<dim3(64, 12), 256, 0, stream>>>(a);
    attn_k<<<dim3(16, 32, 2), 256, 0, stream>>>(a);
    wo_k<<<dim3(128, 4), 256, 0, stream>>>(a);
    ln2_k<<<2048, 256, 0, stream>>>(a);
    ff1_k<<<dim3(64, 16), 256, 0, stream>>>(a);
    ff2_k<<<dim3(128, 4), 256, 0, stream>>>(a);
  }
}

// Round 16
// 210.551 us; speedup vs baseline: 3.0595x; 3.0595x over previous
//
#include <hip/hip_runtime.h>
#include <cmath>

typedef __attribute__((ext_vector_type(8))) __bf16 bf16x8;
typedef __attribute__((ext_vector_type(4))) __bf16 bf16x4;
typedef __attribute__((ext_vector_type(4))) float  f32x4;

constexpr int NB   = 4;
constexpr int SEQ  = 2048;
constexpr int DM   = 256;
constexpr int NH   = 8;
constexpr int DH   = 32;
constexpr int DFF  = 1024;
constexpr int MTOK = NB * SEQ;  // 8192

// ---------------- LayerNorm: fp32 [rows][256] -> bf16 [rows][256] ----------------
__global__ __launch_bounds__(256) void ln_kernel(const float* __restrict__ x,
                                                 const float* __restrict__ g,
                                                 const float* __restrict__ b,
                                                 __bf16* __restrict__ out) {
  int wave = threadIdx.x >> 6, lane = threadIdx.x & 63;
  int row = blockIdx.x * 4 + wave;
  const float* xr = x + (size_t)row * DM;
  f32x4 v = *(const f32x4*)(xr + lane * 4);
  float s  = v[0] + v[1] + v[2] + v[3];
  float sq = v[0]*v[0] + v[1]*v[1] + v[2]*v[2] + v[3]*v[3];
  #pragma unroll
  for (int off = 1; off < 64; off <<= 1) {
    s  += __shfl_xor(s, off);
    sq += __shfl_xor(sq, off);
  }
  float mu  = s * (1.0f / DM);
  float var = sq * (1.0f / DM) - mu * mu;
  float rs  = rsqrtf(var + 1e-5f);
  f32x4 gv = *(const f32x4*)(g + lane * 4);
  f32x4 bv = *(const f32x4*)(b + lane * 4);
  bf16x4 o;
  #pragma unroll
  for (int i = 0; i < 4; ++i) o[i] = (__bf16)((v[i] - mu) * rs * gv[i] + bv[i]);
  *(bf16x4*)(out + (size_t)row * DM + lane * 4) = o;
}

// ---------------- Fused prep, TIGHT 1D grid (2848 blocks) ----------------
__global__ __launch_bounds__(256) void prep_kernel(
    const float* __restrict__ wq, const float* __restrict__ wk, const float* __restrict__ wv,
    const float* __restrict__ wo, const float* __restrict__ w1, const float* __restrict__ w2,
    const unsigned char* __restrict__ mask, const float* __restrict__ tokens,
    const float* __restrict__ ln1g, const float* __restrict__ ln1b,
    __bf16* __restrict__ wqkvT, __bf16* __restrict__ woT,
    __bf16* __restrict__ w1T, __bf16* __restrict__ w2T,
    float* __restrict__ madd_g, __bf16* __restrict__ xn1) {
  __shared__ float tile[32][33];
  int bid = blockIdx.x;
  int tid = threadIdx.x;
  if (bid >= 800) {
    int row = (bid - 800) * 4 + (tid >> 6);
    int lane = tid & 63;
    const float* xr = tokens + (size_t)row * DM;
    f32x4 v = *(const f32x4*)(xr + lane * 4);
    float s  = v[0] + v[1] + v[2] + v[3];
    float sq = v[0]*v[0] + v[1]*v[1] + v[2]*v[2] + v[3]*v[3];
    #pragma unroll
    for (int off = 1; off < 64; off <<= 1) {
      s  += __shfl_xor(s, off);
      sq += __shfl_xor(sq, off);
    }
    float mu  = s * (1.0f / DM);
    float var = sq * (1.0f / DM) - mu * mu;
    float rs  = rsqrtf(var + 1e-5f);
    f32x4 gv = *(const f32x4*)(ln1g + lane * 4);
    f32x4 bv = *(const f32x4*)(ln1b + lane * 4);
    bf16x4 o;
    #pragma unroll
    for (int i = 0; i < 4; ++i) o[i] = (__bf16)((v[i] - mu) * rs * gv[i] + bv[i]);
    *(bf16x4*)(xn1 + (size_t)row * DM + lane * 4) = o;
    return;
  }
  if (bid >= 768) {
    int idx = (bid - 768) * 256 + tid;
    madd_g[idx] = mask[idx] ? -__builtin_inff() : 0.0f;
    return;
  }
  const float* W; __bf16* Wt; int K, N, n0, k0;
  if (bid < 256) {
    int z = bid >> 6, local = bid & 63;
    K = 256; N = 256;
    n0 = (local & 7) * 32; k0 = (local >> 3) * 32;
    if      (z == 0) { W = wq; Wt = wqkvT;          }
    else if (z == 1) { W = wk; Wt = wqkvT + 65536;  }
    else if (z == 2) { W = wv; Wt = wqkvT + 131072; }
    else             { W = wo; Wt = woT;            }
  } else if (bid < 512) {
    int local = bid - 256;
    W = w1; Wt = w1T; K = 256; N = 1024;
    n0 = (local & 31) * 32; k0 = (local >> 5) * 32;
  } else {
    int local = bid - 512;
    W = w2; Wt = w2T; K = 1024; N = 256;
    n0 = (local & 7) * 32; k0 = (local >> 3) * 32;
  }
  {
    int kl = tid >> 3, n4 = (tid & 7) * 4;
    f32x4 v = *(const f32x4*)(W + (size_t)(k0 + kl) * N + n0 + n4);
    tile[kl][n4 + 0] = v[0]; tile[kl][n4 + 1] = v[1];
    tile[kl][n4 + 2] = v[2]; tile[kl][n4 + 3] = v[3];
  }
  __syncthreads();
  {
    int nl = tid >> 3, k4 = (tid & 7) * 4;
    bf16x4 o;
    #pragma unroll
    for (int i = 0; i < 4; ++i) o[i] = (__bf16)tile[k4 + i][nl];
    *(bf16x4*)(Wt + (size_t)(n0 + nl) * K + k0 + k4) = o;
  }
}

// ---------------- GEMM: C[M][N] = A[M][K](bf16) * Bt[N][K]^T + epilogue ----------------
// AF=1: A built on the fly from split-K attention partials (bf16 partials).
template<int BM, int BN, int EP, int AF = 0>
__global__ __launch_bounds__(256) void gemm_bt(
    const __bf16* __restrict__ A, const __bf16* __restrict__ Bt,
    int M, int N, int K,
    const float* __restrict__ bias,
    const float* __restrict__ bq, const float* __restrict__ bk, const float* __restrict__ bv,
    const float* __restrict__ resid, float* __restrict__ outf,
    __bf16* __restrict__ outb,
    __bf16* __restrict__ outq, __bf16* __restrict__ outk, __bf16* __restrict__ outv,
    const __bf16* __restrict__ Af = nullptr, const float* __restrict__ lpart = nullptr) {
  constexpr int MT = BM / 32, NT = BN / 32;
  constexpr int AP = BM / 32, BP = BN / 32;
  __shared__ __bf16 As[BM * 64];
  __shared__ __bf16 Bs[BN * 64];
  int tid = threadIdx.x;
  int wave = tid >> 6, lane = tid & 63;
  int wm = wave >> 1, wn = wave & 1;
  int quad = lane >> 4, l16 = lane & 15;
  int m0 = blockIdx.x * BM, n0 = blockIdx.y * BN;
  int lrow = lane >> 3;
  int lcg  = ((lane & 7) ^ lrow) * 8;

  auto loadA = [&](int rbase, int kcol) -> bf16x8 {
    int gr = m0 + rbase + lrow;
    if constexpr (AF == 0) {
      return *(const bf16x8*)(A + (size_t)gr * K + kcol);
    } else {
      const __bf16* p0 = Af + (size_t)gr * K + kcol;
      const __bf16* p1 = p0 + (size_t)MTOK * DM;
      bf16x8 a0 = *(const bf16x8*)p0;
      bf16x8 a1 = *(const bf16x8*)p1;
      int bb = gr >> 11, tok = gr & 2047, hh = kcol >> 5;
      float l = lpart[((size_t)bb * NH + hh) * SEQ + tok] +
                lpart[(((size_t)NB + bb) * NH + hh) * SEQ + tok];
      float inv = 1.0f / l;
      bf16x8 o;
      #pragma unroll
      for (int i = 0; i < 8; ++i)
        o[i] = (__bf16)(((float)a0[i] + (float)a1[i]) * inv);
      return o;
    }
  };

  f32x4 acc[MT][NT];
  #pragma unroll
  for (int mt = 0; mt < MT; ++mt)
    #pragma unroll
    for (int nt = 0; nt < NT; ++nt)
      #pragma unroll
      for (int r = 0; r < 4; ++r) acc[mt][nt][r] = 0.0f;

  bf16x8 ap[AP], bp[BP];
  #pragma unroll
  for (int i = 0; i < AP; ++i) ap[i] = loadA(wave * (BM / 4) + i * 8, lcg);
  #pragma unroll
  for (int i = 0; i < BP; ++i) {
    int rbase = wave * (BN / 4) + i * 8;
    bp[i] = *(const bf16x8*)(Bt + (size_t)(n0 + rbase + lrow) * K + lcg);
  }
  #pragma unroll
  for (int i = 0; i < AP; ++i) {
    int rbase = wave * (BM / 4) + i * 8;
    *(bf16x8*)&As[rbase * 64 + lane * 8] = ap[i];
  }
  #pragma unroll
  for (int i = 0; i < BP; ++i) {
    int rbase = wave * (BN / 4) + i * 8;
    *(bf16x8*)&Bs[rbase * 64 + lane * 8] = bp[i];
  }
  __syncthreads();

  for (int kt = 0; kt < K; kt += 64) {
    bool more = (kt + 64) < K;
    if (more) {
      #pragma unroll
      for (int i = 0; i < AP; ++i) ap[i] = loadA(wave * (BM / 4) + i * 8, kt + 64 + lcg);
      #pragma unroll
      for (int i = 0; i < BP; ++i) {
        int rbase = wave * (BN / 4) + i * 8;
        bp[i] = *(const bf16x8*)(Bt + (size_t)(n0 + rbase + lrow) * K + kt + 64 + lcg);
      }
    }
    #pragma unroll
    for (int ks = 0; ks < 2; ++ks) {
      bf16x8 af[MT], bfr[NT];
      #pragma unroll
      for (int mt = 0; mt < MT; ++mt) {
        int row = wm * (BM / 2) + mt * 16 + l16;
        af[mt] = *(const bf16x8*)&As[row * 64 + (((ks * 4 + quad) ^ (l16 & 7)) * 8)];
      }
      #pragma unroll
      for (int nt = 0; nt < NT; ++nt) {
        int row = wn * (BN / 2) + nt * 16 + l16;
        bfr[nt] = *(const bf16x8*)&Bs[row * 64 + (((ks * 4 + quad) ^ (l16 & 7)) * 8)];
      }
      #pragma unroll
      for (int mt = 0; mt < MT; ++mt)
        #pragma unroll
        for (int nt = 0; nt < NT; ++nt)
          acc[mt][nt] = __builtin_amdgcn_mfma_f32_16x16x32_bf16(af[mt], bfr[nt], acc[mt][nt], 0, 0, 0);
    }
    if (more) {
      __syncthreads();
      #pragma unroll
      for (int i = 0; i < AP; ++i) {
        int rbase = wave * (BM / 4) + i * 8;
        *(bf16x8*)&As[rbase * 64 + lane * 8] = ap[i];
      }
      #pragma unroll
      for (int i = 0; i < BP; ++i) {
        int rbase = wave * (BN / 4) + i * 8;
        *(bf16x8*)&Bs[rbase * 64 + lane * 8] = bp[i];
      }
      __syncthreads();
    }
  }

  #pragma unroll
  for (int mt = 0; mt < MT; ++mt)
  #pragma unroll
  for (int nt = 0; nt < NT; ++nt)
  #pragma unroll
  for (int r = 0; r < 4; ++r) {
    int gm = m0 + wm * (BM / 2) + mt * 16 + quad * 4 + r;
    int gn = n0 + wn * (BN / 2) + nt * 16 + l16;
    float v = acc[mt][nt][r];
    if constexpr (EP == 0) {
      int which = gn >> 8, nn = gn & 255;
      const float* bp2 = which == 0 ? bq : (which == 1 ? bk : bv);
      v += bp2[nn];
      int h = nn >> 5, hd = nn & 31;
      int bb = gm >> 11, tok = gm & 2047;
      if (which == 2) {
        outv[(((size_t)(bb * NH + h)) * DH + hd) * SEQ + tok] = (__bf16)v;
      } else {
        __bf16* dst = which == 0 ? outq : outk;
        dst[(((size_t)(bb * NH + h)) * SEQ + tok) * DH + hd] = (__bf16)v;
      }
    } else if constexpr (EP == 1) {
      v += bias[gn] + resid[(size_t)gm * N + gn];
      outf[(size_t)gm * N + gn] = v;
    } else {
      v += bias[gn];
      float v2 = v * v;
      float t = __builtin_amdgcn_exp2f(v * (2.3022082f + 0.10294324f * v2));
      outb[(size_t)gm * N + gn] = (__bf16)(v * t * __builtin_amdgcn_rcpf(t + 1.0f));
    }
  }
}

// ---------------- Flash attention: 32 q/wave, shared 128-key stages, split-K=2 ----------------
// R13 structure (best measured); bf16 O-partials (halves Opart traffic).
__global__ __launch_bounds__(256) void attn_kernel(
    const __bf16* __restrict__ Q, const __bf16* __restrict__ K,
    const __bf16* __restrict__ Vt, const float* __restrict__ madd_g,
    __bf16* __restrict__ Opart, float* __restrict__ lpart) {
  constexpr float C2 = 0.2550350030061664f;  // (1/sqrt(32)) * log2(e)
  __shared__ __bf16 Ks[128][36];      // [key][dh], 72B stride
  __shared__ __bf16 Vs[32][132];      // [dh][key], 264B stride
  __shared__ __bf16 Ps[4][2][16][68]; // [wave][qg][query][key]
  int bh = blockIdx.y;
  int q0 = blockIdx.x * 128;
  int half = blockIdx.z;
  int b  = bh >> 3, h = bh & 7;
  int tid = threadIdx.x;
  int wave = tid >> 6, lane = tid & 63;
  int quad = lane >> 4, l16 = lane & 15;
  const __bf16* Qb = Q  + (size_t)bh * SEQ * DH;
  const __bf16* Kb = K  + (size_t)bh * SEQ * DH;
  const __bf16* Vb = Vt + (size_t)bh * DH * SEQ;
  const float* maddb = madd_g + b * SEQ;
  int qw = q0 + wave * 32;
  int kbase = half * (SEQ / 2);

  bf16x8 qf[2];
  #pragma unroll
  for (int qg = 0; qg < 2; ++qg)
    qf[qg] = *(const bf16x8*)(Qb + (size_t)(qw + qg * 16 + l16) * DH + quad * 8);

  bf16x8 ones;
  #pragma unroll
  for (int i = 0; i < 8; ++i) ones[i] = (__bf16)1.0f;

  f32x4 o[2][2], ol[2];
  #pragma unroll
  for (int qg = 0; qg < 2; ++qg) {
    #pragma unroll
    for (int nt = 0; nt < 2; ++nt)
      #pragma unroll
      for (int r = 0; r < 4; ++r) o[qg][nt][r] = 0.0f;
    #pragma unroll
    for (int r = 0; r < 4; ++r) ol[qg][r] = 0.0f;
  }

  f32x4 zf; zf[0] = zf[1] = zf[2] = zf[3] = 0.0f;

  for (int st = 0; st < 8; ++st) {          // 8 stages x 128 keys = this half
    int kb0 = kbase + st * 128;
    __syncthreads();
    #pragma unroll
    for (int p = 0; p < 2; ++p) {           // stage K: 128 rows x 64B
      int c = p * 256 + tid, row = c >> 2, cg = (c & 3) * 8;
      *(bf16x8*)&Ks[row][cg] = *(const bf16x8*)(Kb + (size_t)(kb0 + row) * DH + cg);
    }
    #pragma unroll
    for (int p = 0; p < 2; ++p) {           // stage V: 32 rows x 256B
      int c = p * 256 + tid, row = c >> 4, cg = (c & 15) * 8;
      *(bf16x8*)&Vs[row][cg] = *(const bf16x8*)(Vb + (size_t)row * SEQ + kb0 + cg);
    }
    __syncthreads();

    #pragma unroll
    for (int sub = 0; sub < 2; ++sub) {     // 2 x 64-key subtiles
      int kl = sub * 64;
      f32x4 s[2][4];
      #pragma unroll
      for (int mt = 0; mt < 4; ++mt) {
        bf16x8 kf = *(const bf16x8*)&Ks[kl + mt * 16 + l16][quad * 8];
        s[0][mt] = __builtin_amdgcn_mfma_f32_16x16x32_bf16(kf, qf[0], zf, 0, 0, 0);
        s[1][mt] = __builtin_amdgcn_mfma_f32_16x16x32_bf16(kf, qf[1], zf, 0, 0, 0);
      }
      #pragma unroll
      for (int mt = 0; mt < 4; ++mt) {
        f32x4 md = *(const f32x4*)(maddb + kb0 + kl + mt * 16 + quad * 4);
        #pragma unroll
        for (int qg = 0; qg < 2; ++qg) {
          bf16x4 pv;
          #pragma unroll
          for (int r = 0; r < 4; ++r)
            pv[r] = (__bf16)__builtin_amdgcn_exp2f(fmaf(s[qg][mt][r], C2, md[r]));
          *(bf16x4*)&Ps[wave][qg][l16][mt * 16 + quad * 4] = pv;
        }
      }
      #pragma unroll
      for (int ks = 0; ks < 2; ++ks) {
        bf16x8 vf[2];
        #pragma unroll
        for (int nt = 0; nt < 2; ++nt)
          vf[nt] = *(const bf16x8*)&Vs[nt * 16 + l16][kl + ks * 32 + quad * 8];
        #pragma unroll
        for (int qg = 0; qg < 2; ++qg) {
          bf16x8 pf = *(const bf16x8*)&Ps[wave][qg][l16][ks * 32 + quad * 8];
          #pragma unroll
          for (int nt = 0; nt < 2; ++nt)
            o[qg][nt] = __builtin_amdgcn_mfma_f32_16x16x32_bf16(pf, vf[nt], o[qg][nt], 0, 0, 0);
          ol[qg] = __builtin_amdgcn_mfma_f32_16x16x32_bf16(pf, ones, ol[qg], 0, 0, 0);
        }
      }
    }
  }

  // store unnormalized bf16 partials
  __bf16* Op = Opart + (size_t)half * MTOK * DM;
  #pragma unroll
  for (int qg = 0; qg < 2; ++qg) {
    #pragma unroll
    for (int nt = 0; nt < 2; ++nt)
      #pragma unroll
      for (int r = 0; r < 4; ++r) {
        int q   = qw + qg * 16 + quad * 4 + r;
        int col = h * DH + nt * 16 + l16;
        Op[((size_t)(b * SEQ + q)) * DM + col] = (__bf16)o[qg][nt][r];
      }
    if (l16 == 0) {
      #pragma unroll
      for (int r = 0; r < 4; ++r)
        lpart[((((size_t)half * NB + b) * NH) + h) * SEQ + qw + qg * 16 + quad * 4 + r] = ol[qg][r];
    }
  }
}

// ---------------- launcher ----------------
extern "C" void kernel_launch(void* const* d_in, const int* in_sizes, int n_in,
                              void* d_out, int out_size, void* d_ws, size_t ws_size,
                              hipStream_t stream) {
  const float* tokens = (const float*)d_in[0];
  const unsigned char* mask = (const unsigned char*)d_in[1];
  const float* ln1g = (const float*)d_in[2];
  const float* ln1b = (const float*)d_in[3];
  const float* wq = (const float*)d_in[4];
  const float* bq = (const float*)d_in[5];
  const float* wk = (const float*)d_in[6];
  const float* bk = (const float*)d_in[7];
  const float* wv = (const float*)d_in[8];
  const float* bv = (const float*)d_in[9];
  const float* wo = (const float*)d_in[10];
  const float* bo = (const float*)d_in[11];
  const float* ln2g = (const float*)d_in[12];
  const float* ln2b = (const float*)d_in[13];
  const float* w1 = (const float*)d_in[14];
  const float* b1 = (const float*)d_in[15];
  const float* w2 = (const float*)d_in[16];
  const float* b2 = (const float*)d_in[17];
  float* out = (float*)d_out;
  char* ws = (char*)d_ws;

  __bf16* wqkvT = (__bf16*)(ws + 0);            // [768][256]
  __bf16* woT   = (__bf16*)(ws + 393216);       // [256][256]
  __bf16* w1T   = (__bf16*)(ws + 524288);       // [1024][256]
  __bf16* w2T   = (__bf16*)(ws + 1048576);      // [256][1024]
  __bf16* xn1   = (__bf16*)(ws + 1572864);      // [8192][256] (dead after QKV)
  float*  lpart = (float*)(ws + 1572864);       // [2][4][8][2048] fp32 (reuses xn1 region)
  __bf16* qb    = (__bf16*)(ws + 5767168);      // [32][2048][32]
  __bf16* kb    = (__bf16*)(ws + 9961472);
  __bf16* vt    = (__bf16*)(ws + 18350080);     // [32][32][2048]
  float*  x1    = (float*)(ws + 26738688);      // [8192][256] fp32
  __bf16* xn2   = (__bf16*)(ws + 35127296);     // [8192][256]
  __bf16* hbuf  = (__bf16*)(ws + 39321600);     // [8192][1024] (FF1 out)
  __bf16* Opart = (__bf16*)(ws + 39321600);     // [2][8192][256] bf16, lifetime-disjoint w/ hbuf
  float*  madd  = (float*)(ws + 56098816);      // [4][2048] fp32

  prep_kernel<<<2848, 256, 0, stream>>>(
      wq, wk, wv, wo, w1, w2, mask, tokens, ln1g, ln1b,
      wqkvT, woT, w1T, w2T, madd, xn1);

  gemm_bt<128, 64, 0><<<dim3(64, 12), 256, 0, stream>>>(
      xn1, wqkvT, MTOK, 768, 256, nullptr, bq, bk, bv,
      nullptr, nullptr, nullptr, qb, kb, vt);

  attn_kernel<<<dim3(SEQ / 128, 32, 2), 256, 0, stream>>>(qb, kb, vt, madd, Opart, lpart);

  gemm_bt<64, 64, 1, 1><<<dim3(128, 4), 256, 0, stream>>>(
      nullptr, woT, MTOK, 256, 256, bo, nullptr, nullptr, nullptr,
      tokens, x1, nullptr, nullptr, nullptr, nullptr, Opart, lpart);

  ln_kernel<<<MTOK / 4, 256, 0, stream>>>(x1, ln2g, ln2b, xn2);

  gemm_bt<128, 128, 2><<<dim3(64, 8), 256, 0, stream>>>(
      xn2, w1T, MTOK, DFF, 256, b1, nullptr, nullptr, nullptr,
      nullptr, nullptr, hbuf, nullptr, nullptr, nullptr);

  gemm_bt<64, 64, 1><<<dim3(128, 4), 256, 0, stream>>>(
      hbuf, w2T, MTOK, 256, DFF, b2, nullptr, nullptr, nullptr,
      x1, out, nullptr, nullptr, nullptr, nullptr);
}

// Round 17
// 189.666 us; speedup vs baseline: 3.3964x; 1.1101x over previous
//
#include <hip/hip_runtime.h>
#include <cmath>

typedef __attribute__((ext_vector_type(8))) __bf16 bf16x8;
typedef __attribute__((ext_vector_type(4))) __bf16 bf16x4;
typedef __attribute__((ext_vector_type(4))) float  f32x4;

constexpr int NB   = 4;
constexpr int SEQ  = 2048;
constexpr int DM   = 256;
constexpr int NH   = 8;
constexpr int DH   = 32;
constexpr int DFF  = 1024;
constexpr int MTOK = NB * SEQ;  // 8192

// ---------------- LayerNorm: fp32 [rows][256] -> bf16 [rows][256] ----------------
__global__ __launch_bounds__(256) void ln_kernel(const float* __restrict__ x,
                                                 const float* __restrict__ g,
                                                 const float* __restrict__ b,
                                                 __bf16* __restrict__ out) {
  int wave = threadIdx.x >> 6, lane = threadIdx.x & 63;
  int row = blockIdx.x * 4 + wave;
  const float* xr = x + (size_t)row * DM;
  f32x4 v = *(const f32x4*)(xr + lane * 4);
  float s  = v[0] + v[1] + v[2] + v[3];
  float sq = v[0]*v[0] + v[1]*v[1] + v[2]*v[2] + v[3]*v[3];
  #pragma unroll
  for (int off = 1; off < 64; off <<= 1) {
    s  += __shfl_xor(s, off);
    sq += __shfl_xor(sq, off);
  }
  float mu  = s * (1.0f / DM);
  float var = sq * (1.0f / DM) - mu * mu;
  float rs  = rsqrtf(var + 1e-5f);
  f32x4 gv = *(const f32x4*)(g + lane * 4);
  f32x4 bv = *(const f32x4*)(b + lane * 4);
  bf16x4 o;
  #pragma unroll
  for (int i = 0; i < 4; ++i) o[i] = (__bf16)((v[i] - mu) * rs * gv[i] + bv[i]);
  *(bf16x4*)(out + (size_t)row * DM + lane * 4) = o;
}

// ---------------- Fused prep, TIGHT 1D grid (2848 blocks) ----------------
__global__ __launch_bounds__(256) void prep_kernel(
    const float* __restrict__ wq, const float* __restrict__ wk, const float* __restrict__ wv,
    const float* __restrict__ wo, const float* __restrict__ w1, const float* __restrict__ w2,
    const unsigned char* __restrict__ mask, const float* __restrict__ tokens,
    const float* __restrict__ ln1g, const float* __restrict__ ln1b,
    __bf16* __restrict__ wqkvT, __bf16* __restrict__ woT,
    __bf16* __restrict__ w1T, __bf16* __restrict__ w2T,
    float* __restrict__ madd_g, __bf16* __restrict__ xn1) {
  __shared__ float tile[32][33];
  int bid = blockIdx.x;
  int tid = threadIdx.x;
  if (bid >= 800) {
    int row = (bid - 800) * 4 + (tid >> 6);
    int lane = tid & 63;
    const float* xr = tokens + (size_t)row * DM;
    f32x4 v = *(const f32x4*)(xr + lane * 4);
    float s  = v[0] + v[1] + v[2] + v[3];
    float sq = v[0]*v[0] + v[1]*v[1] + v[2]*v[2] + v[3]*v[3];
    #pragma unroll
    for (int off = 1; off < 64; off <<= 1) {
      s  += __shfl_xor(s, off);
      sq += __shfl_xor(sq, off);
    }
    float mu  = s * (1.0f / DM);
    float var = sq * (1.0f / DM) - mu * mu;
    float rs  = rsqrtf(var + 1e-5f);
    f32x4 gv = *(const f32x4*)(ln1g + lane * 4);
    f32x4 bv = *(const f32x4*)(ln1b + lane * 4);
    bf16x4 o;
    #pragma unroll
    for (int i = 0; i < 4; ++i) o[i] = (__bf16)((v[i] - mu) * rs * gv[i] + bv[i]);
    *(bf16x4*)(xn1 + (size_t)row * DM + lane * 4) = o;
    return;
  }
  if (bid >= 768) {
    int idx = (bid - 768) * 256 + tid;
    madd_g[idx] = mask[idx] ? -__builtin_inff() : 0.0f;
    return;
  }
  const float* W; __bf16* Wt; int K, N, n0, k0;
  if (bid < 256) {
    int z = bid >> 6, local = bid & 63;
    K = 256; N = 256;
    n0 = (local & 7) * 32; k0 = (local >> 3) * 32;
    if      (z == 0) { W = wq; Wt = wqkvT;          }
    else if (z == 1) { W = wk; Wt = wqkvT + 65536;  }
    else if (z == 2) { W = wv; Wt = wqkvT + 131072; }
    else             { W = wo; Wt = woT;            }
  } else if (bid < 512) {
    int local = bid - 256;
    W = w1; Wt = w1T; K = 256; N = 1024;
    n0 = (local & 31) * 32; k0 = (local >> 5) * 32;
  } else {
    int local = bid - 512;
    W = w2; Wt = w2T; K = 1024; N = 256;
    n0 = (local & 7) * 32; k0 = (local >> 3) * 32;
  }
  {
    int kl = tid >> 3, n4 = (tid & 7) * 4;
    f32x4 v = *(const f32x4*)(W + (size_t)(k0 + kl) * N + n0 + n4);
    tile[kl][n4 + 0] = v[0]; tile[kl][n4 + 1] = v[1];
    tile[kl][n4 + 2] = v[2]; tile[kl][n4 + 3] = v[3];
  }
  __syncthreads();
  {
    int nl = tid >> 3, k4 = (tid & 7) * 4;
    bf16x4 o;
    #pragma unroll
    for (int i = 0; i < 4; ++i) o[i] = (__bf16)tile[k4 + i][nl];
    *(bf16x4*)(Wt + (size_t)(n0 + nl) * K + k0 + k4) = o;
  }
}

// ---------------- GEMM: C[M][N] = A[M][K](bf16) * Bt[N][K]^T + epilogue ----------------
// AF=1: A built on the fly from split-K attention partials (fp32 partials).
template<int BM, int BN, int EP, int AF = 0>
__global__ __launch_bounds__(256) void gemm_bt(
    const __bf16* __restrict__ A, const __bf16* __restrict__ Bt,
    int M, int N, int K,
    const float* __restrict__ bias,
    const float* __restrict__ bq, const float* __restrict__ bk, const float* __restrict__ bv,
    const float* __restrict__ resid, float* __restrict__ outf,
    __bf16* __restrict__ outb,
    __bf16* __restrict__ outq, __bf16* __restrict__ outk, __bf16* __restrict__ outv,
    const float* __restrict__ Af = nullptr, const float* __restrict__ lpart = nullptr) {
  constexpr int MT = BM / 32, NT = BN / 32;
  constexpr int AP = BM / 32, BP = BN / 32;
  __shared__ __bf16 As[BM * 64];
  __shared__ __bf16 Bs[BN * 64];
  int tid = threadIdx.x;
  int wave = tid >> 6, lane = tid & 63;
  int wm = wave >> 1, wn = wave & 1;
  int quad = lane >> 4, l16 = lane & 15;
  int m0 = blockIdx.x * BM, n0 = blockIdx.y * BN;
  int lrow = lane >> 3;
  int lcg  = ((lane & 7) ^ lrow) * 8;

  auto loadA = [&](int rbase, int kcol) -> bf16x8 {
    int gr = m0 + rbase + lrow;
    if constexpr (AF == 0) {
      return *(const bf16x8*)(A + (size_t)gr * K + kcol);
    } else {
      const float* p0 = Af + (size_t)gr * K + kcol;
      const float* p1 = p0 + (size_t)MTOK * DM;
      f32x4 a0 = *(const f32x4*)p0, a0b = *(const f32x4*)(p0 + 4);
      f32x4 a1 = *(const f32x4*)p1, a1b = *(const f32x4*)(p1 + 4);
      int bb = gr >> 11, tok = gr & 2047, hh = kcol >> 5;
      float l = lpart[((size_t)bb * NH + hh) * SEQ + tok] +
                lpart[(((size_t)NB + bb) * NH + hh) * SEQ + tok];
      float inv = 1.0f / l;
      bf16x8 o;
      #pragma unroll
      for (int i = 0; i < 4; ++i) {
        o[i]     = (__bf16)((a0[i]  + a1[i])  * inv);
        o[i + 4] = (__bf16)((a0b[i] + a1b[i]) * inv);
      }
      return o;
    }
  };

  f32x4 acc[MT][NT];
  #pragma unroll
  for (int mt = 0; mt < MT; ++mt)
    #pragma unroll
    for (int nt = 0; nt < NT; ++nt)
      #pragma unroll
      for (int r = 0; r < 4; ++r) acc[mt][nt][r] = 0.0f;

  bf16x8 ap[AP], bp[BP];
  #pragma unroll
  for (int i = 0; i < AP; ++i) ap[i] = loadA(wave * (BM / 4) + i * 8, lcg);
  #pragma unroll
  for (int i = 0; i < BP; ++i) {
    int rbase = wave * (BN / 4) + i * 8;
    bp[i] = *(const bf16x8*)(Bt + (size_t)(n0 + rbase + lrow) * K + lcg);
  }
  #pragma unroll
  for (int i = 0; i < AP; ++i) {
    int rbase = wave * (BM / 4) + i * 8;
    *(bf16x8*)&As[rbase * 64 + lane * 8] = ap[i];
  }
  #pragma unroll
  for (int i = 0; i < BP; ++i) {
    int rbase = wave * (BN / 4) + i * 8;
    *(bf16x8*)&Bs[rbase * 64 + lane * 8] = bp[i];
  }
  __syncthreads();

  for (int kt = 0; kt < K; kt += 64) {
    bool more = (kt + 64) < K;
    if (more) {
      #pragma unroll
      for (int i = 0; i < AP; ++i) ap[i] = loadA(wave * (BM / 4) + i * 8, kt + 64 + lcg);
      #pragma unroll
      for (int i = 0; i < BP; ++i) {
        int rbase = wave * (BN / 4) + i * 8;
        bp[i] = *(const bf16x8*)(Bt + (size_t)(n0 + rbase + lrow) * K + kt + 64 + lcg);
      }
    }
    #pragma unroll
    for (int ks = 0; ks < 2; ++ks) {
      bf16x8 af[MT], bfr[NT];
      #pragma unroll
      for (int mt = 0; mt < MT; ++mt) {
        int row = wm * (BM / 2) + mt * 16 + l16;
        af[mt] = *(const bf16x8*)&As[row * 64 + (((ks * 4 + quad) ^ (l16 & 7)) * 8)];
      }
      #pragma unroll
      for (int nt = 0; nt < NT; ++nt) {
        int row = wn * (BN / 2) + nt * 16 + l16;
        bfr[nt] = *(const bf16x8*)&Bs[row * 64 + (((ks * 4 + quad) ^ (l16 & 7)) * 8)];
      }
      #pragma unroll
      for (int mt = 0; mt < MT; ++mt)
        #pragma unroll
        for (int nt = 0; nt < NT; ++nt)
          acc[mt][nt] = __builtin_amdgcn_mfma_f32_16x16x32_bf16(af[mt], bfr[nt], acc[mt][nt], 0, 0, 0);
    }
    if (more) {
      __syncthreads();
      #pragma unroll
      for (int i = 0; i < AP; ++i) {
        int rbase = wave * (BM / 4) + i * 8;
        *(bf16x8*)&As[rbase * 64 + lane * 8] = ap[i];
      }
      #pragma unroll
      for (int i = 0; i < BP; ++i) {
        int rbase = wave * (BN / 4) + i * 8;
        *(bf16x8*)&Bs[rbase * 64 + lane * 8] = bp[i];
      }
      __syncthreads();
    }
  }

  #pragma unroll
  for (int mt = 0; mt < MT; ++mt)
  #pragma unroll
  for (int nt = 0; nt < NT; ++nt)
  #pragma unroll
  for (int r = 0; r < 4; ++r) {
    int gm = m0 + wm * (BM / 2) + mt * 16 + quad * 4 + r;
    int gn = n0 + wn * (BN / 2) + nt * 16 + l16;
    float v = acc[mt][nt][r];
    if constexpr (EP == 0) {
      int which = gn >> 8, nn = gn & 255;
      const float* bp2 = which == 0 ? bq : (which == 1 ? bk : bv);
      v += bp2[nn];
      int h = nn >> 5, hd = nn & 31;
      int bb = gm >> 11, tok = gm & 2047;
      if (which == 2) {
        outv[(((size_t)(bb * NH + h)) * DH + hd) * SEQ + tok] = (__bf16)v;
      } else {
        __bf16* dst = which == 0 ? outq : outk;
        dst[(((size_t)(bb * NH + h)) * SEQ + tok) * DH + hd] = (__bf16)v;
      }
    } else if constexpr (EP == 1) {
      v += bias[gn] + resid[(size_t)gm * N + gn];
      outf[(size_t)gm * N + gn] = v;
    } else {
      v += bias[gn];
      float v2 = v * v;
      float t = __builtin_amdgcn_exp2f(v * (2.3022082f + 0.10294324f * v2));
      outb[(size_t)gm * N + gn] = (__bf16)(v * t * __builtin_amdgcn_rcpf(t + 1.0f));
    }
  }
}

// ---------------- Flash attention (R10/R12 best-measured): 32 q/wave, 128-key stages, split-K=2 ----------------
// grid (bh=32, qchunk=16, half=2), fp32 O-partials. Measured 47.0-50.5 us across 3 runs.
__global__ __launch_bounds__(256) void attn_kernel(
    const __bf16* __restrict__ Q, const __bf16* __restrict__ K,
    const __bf16* __restrict__ Vt, const float* __restrict__ madd_g,
    float* __restrict__ Opart, float* __restrict__ lpart) {
  constexpr float C2 = 0.2550350030061664f;  // (1/sqrt(32)) * log2(e)
  __shared__ __bf16 Ks[128][36];      // [key][dh], 72B stride
  __shared__ __bf16 Vs[32][132];      // [dh][key], 264B stride
  __shared__ __bf16 Ps[4][2][16][68]; // [wave][qg][query][key]
  int bh = blockIdx.x;
  int q0 = blockIdx.y * 128;
  int half = blockIdx.z;
  int b  = bh >> 3, h = bh & 7;
  int tid = threadIdx.x;
  int wave = tid >> 6, lane = tid & 63;
  int quad = lane >> 4, l16 = lane & 15;
  const __bf16* Qb = Q  + (size_t)bh * SEQ * DH;
  const __bf16* Kb = K  + (size_t)bh * SEQ * DH;
  const __bf16* Vb = Vt + (size_t)bh * DH * SEQ;
  const float* maddb = madd_g + b * SEQ;
  int qw = q0 + wave * 32;
  int kbase = half * (SEQ / 2);

  bf16x8 qf[2];
  #pragma unroll
  for (int qg = 0; qg < 2; ++qg)
    qf[qg] = *(const bf16x8*)(Qb + (size_t)(qw + qg * 16 + l16) * DH + quad * 8);

  bf16x8 ones;
  #pragma unroll
  for (int i = 0; i < 8; ++i) ones[i] = (__bf16)1.0f;

  f32x4 o[2][2], ol[2];
  #pragma unroll
  for (int qg = 0; qg < 2; ++qg) {
    #pragma unroll
    for (int nt = 0; nt < 2; ++nt)
      #pragma unroll
      for (int r = 0; r < 4; ++r) o[qg][nt][r] = 0.0f;
    #pragma unroll
    for (int r = 0; r < 4; ++r) ol[qg][r] = 0.0f;
  }

  f32x4 zf; zf[0] = zf[1] = zf[2] = zf[3] = 0.0f;

  for (int st = 0; st < 8; ++st) {          // 8 stages x 128 keys = this half
    int kb0 = kbase + st * 128;
    __syncthreads();
    #pragma unroll
    for (int p = 0; p < 2; ++p) {           // stage K: 128 rows x 64B
      int c = p * 256 + tid, row = c >> 2, cg = (c & 3) * 8;
      *(bf16x8*)&Ks[row][cg] = *(const bf16x8*)(Kb + (size_t)(kb0 + row) * DH + cg);
    }
    #pragma unroll
    for (int p = 0; p < 2; ++p) {           // stage V: 32 rows x 256B
      int c = p * 256 + tid, row = c >> 4, cg = (c & 15) * 8;
      *(bf16x8*)&Vs[row][cg] = *(const bf16x8*)(Vb + (size_t)row * SEQ + kb0 + cg);
    }
    __syncthreads();

    #pragma unroll
    for (int sub = 0; sub < 2; ++sub) {     // 2 x 64-key subtiles
      int kl = sub * 64;
      f32x4 s[2][4];
      #pragma unroll
      for (int mt = 0; mt < 4; ++mt) {
        bf16x8 kf = *(const bf16x8*)&Ks[kl + mt * 16 + l16][quad * 8];
        s[0][mt] = __builtin_amdgcn_mfma_f32_16x16x32_bf16(kf, qf[0], zf, 0, 0, 0);
        s[1][mt] = __builtin_amdgcn_mfma_f32_16x16x32_bf16(kf, qf[1], zf, 0, 0, 0);
      }
      #pragma unroll
      for (int mt = 0; mt < 4; ++mt) {
        f32x4 md = *(const f32x4*)(maddb + kb0 + kl + mt * 16 + quad * 4);
        #pragma unroll
        for (int qg = 0; qg < 2; ++qg) {
          bf16x4 pv;
          #pragma unroll
          for (int r = 0; r < 4; ++r)
            pv[r] = (__bf16)__builtin_amdgcn_exp2f(fmaf(s[qg][mt][r], C2, md[r]));
          *(bf16x4*)&Ps[wave][qg][l16][mt * 16 + quad * 4] = pv;
        }
      }
      #pragma unroll
      for (int ks = 0; ks < 2; ++ks) {
        bf16x8 vf[2];
        #pragma unroll
        for (int nt = 0; nt < 2; ++nt)
          vf[nt] = *(const bf16x8*)&Vs[nt * 16 + l16][kl + ks * 32 + quad * 8];
        #pragma unroll
        for (int qg = 0; qg < 2; ++qg) {
          bf16x8 pf = *(const bf16x8*)&Ps[wave][qg][l16][ks * 32 + quad * 8];
          #pragma unroll
          for (int nt = 0; nt < 2; ++nt)
            o[qg][nt] = __builtin_amdgcn_mfma_f32_16x16x32_bf16(pf, vf[nt], o[qg][nt], 0, 0, 0);
          ol[qg] = __builtin_amdgcn_mfma_f32_16x16x32_bf16(pf, ones, ol[qg], 0, 0, 0);
        }
      }
    }
  }

  // store unnormalized fp32 partials
  float* Op = Opart + (size_t)half * MTOK * DM;
  #pragma unroll
  for (int qg = 0; qg < 2; ++qg) {
    #pragma unroll
    for (int nt = 0; nt < 2; ++nt)
      #pragma unroll
      for (int r = 0; r < 4; ++r) {
        int q   = qw + qg * 16 + quad * 4 + r;
        int col = h * DH + nt * 16 + l16;
        Op[((size_t)(b * SEQ + q)) * DM + col] = o[qg][nt][r];
      }
    if (l16 == 0) {
      #pragma unroll
      for (int r = 0; r < 4; ++r)
        lpart[((((size_t)half * NB + b) * NH) + h) * SEQ + qw + qg * 16 + quad * 4 + r] = ol[qg][r];
    }
  }
}

// ---------------- launcher ----------------
extern "C" void kernel_launch(void* const* d_in, const int* in_sizes, int n_in,
                              void* d_out, int out_size, void* d_ws, size_t ws_size,
                              hipStream_t stream) {
  const float* tokens = (const float*)d_in[0];
  const unsigned char* mask = (const unsigned char*)d_in[1];
  const float* ln1g = (const float*)d_in[2];
  const float* ln1b = (const float*)d_in[3];
  const float* wq = (const float*)d_in[4];
  const float* bq = (const float*)d_in[5];
  const float* wk = (const float*)d_in[6];
  const float* bk = (const float*)d_in[7];
  const float* wv = (const float*)d_in[8];
  const float* bv = (const float*)d_in[9];
  const float* wo = (const float*)d_in[10];
  const float* bo = (const float*)d_in[11];
  const float* ln2g = (const float*)d_in[12];
  const float* ln2b = (const float*)d_in[13];
  const float* w1 = (const float*)d_in[14];
  const float* b1 = (const float*)d_in[15];
  const float* w2 = (const float*)d_in[16];
  const float* b2 = (const float*)d_in[17];
  float* out = (float*)d_out;
  char* ws = (char*)d_ws;

  __bf16* wqkvT = (__bf16*)(ws + 0);            // [768][256]
  __bf16* woT   = (__bf16*)(ws + 393216);       // [256][256]
  __bf16* w1T   = (__bf16*)(ws + 524288);       // [1024][256]
  __bf16* w2T   = (__bf16*)(ws + 1048576);      // [256][1024]
  __bf16* xn1   = (__bf16*)(ws + 1572864);      // [8192][256] (dead after QKV)
  float*  lpart = (float*)(ws + 1572864);       // [2][4][8][2048] fp32 (reuses xn1 region)
  __bf16* qb    = (__bf16*)(ws + 5767168);      // [32][2048][32]
  __bf16* kb    = (__bf16*)(ws + 9961472);
  __bf16* vt    = (__bf16*)(ws + 18350080);     // [32][32][2048]
  float*  x1    = (float*)(ws + 26738688);      // [8192][256] fp32
  __bf16* xn2   = (__bf16*)(ws + 35127296);     // [8192][256]
  __bf16* hbuf  = (__bf16*)(ws + 39321600);     // [8192][1024] (FF1 out)
  float*  Opart = (float*)(ws + 39321600);      // [2][8192][256] fp32, lifetime-disjoint w/ hbuf
  float*  madd  = (float*)(ws + 56098816);      // [4][2048] fp32

  prep_kernel<<<2848, 256, 0, stream>>>(
      wq, wk, wv, wo, w1, w2, mask, tokens, ln1g, ln1b,
      wqkvT, woT, w1T, w2T, madd, xn1);

  gemm_bt<128, 64, 0><<<dim3(64, 12), 256, 0, stream>>>(
      xn1, wqkvT, MTOK, 768, 256, nullptr, bq, bk, bv,
      nullptr, nullptr, nullptr, qb, kb, vt);

  attn_kernel<<<dim3(32, SEQ / 128, 2), 256, 0, stream>>>(qb, kb, vt, madd, Opart, lpart);

  gemm_bt<64, 64, 1, 1><<<dim3(128, 4), 256, 0, stream>>>(
      nullptr, woT, MTOK, 256, 256, bo, nullptr, nullptr, nullptr,
      tokens, x1, nullptr, nullptr, nullptr, nullptr, Opart, lpart);

  ln_kernel<<<MTOK / 4, 256, 0, stream>>>(x1, ln2g, ln2b, xn2);

  gemm_bt<128, 128, 2><<<dim3(64, 8), 256, 0, stream>>>(
      xn2, w1T, MTOK, DFF, 256, b1, nullptr, nullptr, nullptr,
      nullptr, nullptr, hbuf, nullptr, nullptr, nullptr);

  gemm_bt<64, 64, 1><<<dim3(128, 4), 256, 0, stream>>>(
      hbuf, w2T, MTOK, 256, DFF, b2, nullptr, nullptr, nullptr,
      x1, out, nullptr, nullptr, nullptr, nullptr);
}